// Round 11
// baseline (124.215 us; speedup 1.0000x reference)
//
#include <hip/hip_runtime.h>

// PendulumSolver: B=65536 independent driven pendulums, RK4, 999 steps.
// Round 11: occupancy is thread-count-pinned (1 wave/SIMD) -> VGPRs are FREE.
//   - 8-step unrolled body (2 float4 stores), forcing for all 8 steps grouped
//     FIRST (24 HW-cos + packed reductions, state-independent) so the
//     scheduler has a big pool of independent work to fill the serial RK4
//     chain's trans/FMA latency bubbles (R6-R10: ~25% stall).
//   - scalar ks-combine (R10's packed combine required v_mov pairs to build
//     vectors from chain scalars - net loss).
//   - s2 via full packed to_rev2(th,th2) (R6's exact form); s3/s4 via R9's
//     delta form fma(thX - th, 1/2pi, rvth).
// Numerics: every per-step expression bit-identical to a previously PASSED
// round (absmax frozen at 0.0625 across 10 impls). Argument-class changes
// (t-chaining, reassociation of tp*t, constant-dy) remain rejected.

typedef float v2f __attribute__((ext_vector_type(2)));

__device__ __forceinline__ v2f vfma2(v2f a, v2f b, v2f c) {
#if __has_builtin(__builtin_elementwise_fma)
    return __builtin_elementwise_fma(a, b, c);
#else
    v2f r; r.x = fmaf(a.x, b.x, c.x); r.y = fmaf(a.y, b.y, c.y); return r;
#endif
}
__device__ __forceinline__ v2f splat2(float v) { v2f r; r.x = v; r.y = v; return r; }

#define CHI_F 0.15915494309189533577f
#define CLO_F ((float)(0.15915494309189533577 - (double)0.15915494309189533577f))
#define MAGIC_F 12582912.0f   // 1.5 * 2^23

// Packed radians -> revolutions; per-lane ops identical to scalar to_rev1.
__device__ __forceinline__ v2f to_rev2(v2f x) {
    v2f nb = vfma2(x, splat2(CHI_F), splat2(MAGIC_F));
    v2f n  = nb - splat2(MAGIC_F);
    v2f r  = vfma2(x, splat2(CHI_F), -n);
    return vfma2(x, splat2(CLO_F), r);
}

__device__ __forceinline__ float hw_sin_rev(float x) {
#if __has_builtin(__builtin_amdgcn_sinf)
    return __builtin_amdgcn_sinf(x);
#else
    return __sinf(x * 6.28318530717958647692f);
#endif
}
__device__ __forceinline__ float hw_cos_rev(float x) {
#if __has_builtin(__builtin_amdgcn_cosf)
    return __builtin_amdgcn_cosf(x);
#else
    return __cosf(x * 6.28318530717958647692f);
#endif
}

__global__ __launch_bounds__(256) void pend_kernel(
    const float* __restrict__ init,    // (B,2) theta, thdot
    const float* __restrict__ params,  // (B,4) omega, gamma, A, phi
    float* __restrict__ out,           // (B,1000)
    int B)
{
    int b = blockIdx.x * blockDim.x + threadIdx.x;
    if (b >= B) return;

    float th = init[2 * b + 0];
    float w  = init[2 * b + 1];
    const float omega = params[4 * b + 0];
    const float gamma = params[4 * b + 1];
    const float A     = params[4 * b + 2];
    const float phi   = params[4 * b + 3];

    const float dt  = 0.01f;
    const float hdt = 0.5f * dt;
    const float dt6 = dt / 6.0f;
    const float om2 = omega * omega;
    const float Fco = (A * omega) * omega;
    const float tp  = 6.28318530717958647692f * phi;

    v2f hd2; hd2.x = hdt; hd2.y = dt;      // (hdt, dt)

    float4* out4 = (float4*)(out + (size_t)b * 1000);

    float fk = 0.0f;                       // tracks (float)k exactly

    // Forcing cosines for time index fkv: c1 = cos(tp*t), c2 = cos(tp*(t+hdt)),
    // c4 = cos(tp*(t+dt)); args bit-identical to R9/R10.
    auto forcing = [&](float fkv, float rvy1_in, float& c1o, float& c2o,
                       float& c4o) {
        float t   = fkv * dt;
        v2f t23   = splat2(t) + hd2;
        float y1  = tp * t;
        v2f y23   = splat2(tp) * t23;
        v2f dy    = y23 - splat2(y1);                    // Sterbenz-exact
        v2f rvy   = vfma2(dy, splat2(CHI_F), splat2(rvy1_in));
        c1o = hw_cos_rev(rvy1_in);
        c2o = hw_cos_rev(rvy.x);
        c4o = hw_cos_rev(rvy.y);
    };
    // y1 reduction for a pair of adjacent step indices (packed).
    auto rvy1_pair = [&](float fkv) -> v2f {
        v2f fkp; fkp.x = fkv; fkp.y = fkv + 1.0f;
        v2f tpr = fkp * splat2(dt);
        v2f y1p = splat2(tp) * tpr;
        return to_rev2(y1p);
    };

    // One RK4 chain step consuming precomputed forcing (c1,c2,c4).
    auto step = [&](float c1, float c2, float c4) -> float {
        float th2 = fmaf(hdt, w, th);
        v2f pr; pr.x = th; pr.y = th2;
        v2f rvp = to_rev2(pr);                 // (rvth, rvth2) — R6 form
        float sth = hw_sin_rev(rvp.x);
        float s2  = hw_sin_rev(rvp.y);

        float a1  = Fco * c1 - gamma * w   - om2 * sth;
        float w2_ = fmaf(hdt, a1, w);
        float a2  = Fco * c2 - gamma * w2_ - om2 * s2;
        float th3 = fmaf(hdt, w2_, th);
        float s3  = hw_sin_rev(fmaf(th3 - th, CHI_F, rvp.x));
        float w3_ = fmaf(hdt, a2, w);
        float a3  = Fco * c2 - gamma * w3_ - om2 * s3;
        float th4 = fmaf(dt, w3_, th);
        float s4  = hw_sin_rev(fmaf(th4 - th, CHI_F, rvp.x));
        float w4_ = fmaf(dt, a3, w);
        float a4  = Fco * c4 - gamma * w4_ - om2 * s4;

        float ks_th = w  + 2.0f * w2_ + 2.0f * w3_ + w4_;   // scalar, R9 form
        float ks_w  = a1 + 2.0f * a2  + 2.0f * a3  + a4;
        th = fmaf(dt6, ks_th, th);
        w  = fmaf(dt6, ks_w,  w);
        return th;
    };

    // ---- prologue: steps 0..2, store out4[0] = (th0, th1, th2, th3) ----
    float4 ob;
    ob.x = th;
    {
        v2f rp = rvy1_pair(0.0f);
        float c1, c2, c4;
        forcing(0.0f, rp.x, c1, c2, c4); ob.y = step(c1, c2, c4);
        forcing(1.0f, rp.y, c1, c2, c4); ob.z = step(c1, c2, c4);
        v2f rp2 = rvy1_pair(2.0f);
        forcing(2.0f, rp2.x, c1, c2, c4); ob.w = step(c1, c2, c4);
        out4[0] = ob;
    }
    fk = 3.0f;

    // ---- 124 bodies x 8 steps: forcing for all 8 steps first, then chain ----
    for (int j = 0; j < 124; ++j) {
        float C1[8], C2[8], C4[8];
        #pragma unroll
        for (int s = 0; s < 8; s += 2) {
            v2f rp = rvy1_pair(fk + (float)s);
            forcing(fk + (float)s,        rp.x, C1[s],     C2[s],     C4[s]);
            forcing(fk + (float)(s + 1),  rp.y, C1[s + 1], C2[s + 1], C4[s + 1]);
        }
        ob.x = step(C1[0], C2[0], C4[0]);
        ob.y = step(C1[1], C2[1], C4[1]);
        ob.z = step(C1[2], C2[2], C4[2]);
        ob.w = step(C1[3], C2[3], C4[3]);
        out4[2 * j + 1] = ob;
        ob.x = step(C1[4], C2[4], C4[4]);
        ob.y = step(C1[5], C2[5], C4[5]);
        ob.z = step(C1[6], C2[6], C4[6]);
        ob.w = step(C1[7], C2[7], C4[7]);
        out4[2 * j + 2] = ob;
        fk += 8.0f;
    }

    // ---- epilogue: steps 995..998, store out4[249] ----
    {
        float C1[4], C2[4], C4[4];
        v2f rp = rvy1_pair(fk);
        forcing(fk,        rp.x, C1[0], C2[0], C4[0]);
        forcing(fk + 1.0f, rp.y, C1[1], C2[1], C4[1]);
        v2f rp2 = rvy1_pair(fk + 2.0f);
        forcing(fk + 2.0f, rp2.x, C1[2], C2[2], C4[2]);
        forcing(fk + 3.0f, rp2.y, C1[3], C2[3], C4[3]);
        ob.x = step(C1[0], C2[0], C4[0]);
        ob.y = step(C1[1], C2[1], C4[1]);
        ob.z = step(C1[2], C2[2], C4[2]);
        ob.w = step(C1[3], C2[3], C4[3]);
        out4[249] = ob;
    }
}

extern "C" void kernel_launch(void* const* d_in, const int* in_sizes, int n_in,
                              void* d_out, int out_size, void* d_ws, size_t ws_size,
                              hipStream_t stream) {
    const float* init   = (const float*)d_in[0];
    const float* params = (const float*)d_in[1];
    float* out = (float*)d_out;
    int B = in_sizes[0] / 2;

    int block = 256;
    int grid  = (B + block - 1) / block;
    hipLaunchKernelGGL(pend_kernel, dim3(grid), dim3(block), 0, stream,
                       init, params, out, B);
}

// Round 12
// 122.715 us; speedup vs baseline: 1.0122x; 1.0122x over previous
//
#include <hip/hip_runtime.h>

// PendulumSolver: B=65536 independent driven pendulums, RK4, 999 steps.
// Round 12: R10 (best, 120.5us) with the ks-combine/state-update reverted to
// SCALAR form (R9/R11's, passed): R10's packed combine needed ~6-8 v_movs to
// gather chain scalars into vector pairs, costing more than the 4 packed ops
// saved. Everything else identical to R10.
// Calibration from 11 rounds: VALU slot ~2cyc, trans ~16cyc/wave64 -> the 7
// exact-argument trans ops are ~half of busy; recons are break-even at best
// (R5 measured losing). Scheduling restructures (R7/R8/R11) all failed:
// only instruction-count reduction wins.
// Numerics: every expression bit-identical to a previously PASSED round
// (absmax frozen at 0.0625 across 11 impls).

typedef float v2f __attribute__((ext_vector_type(2)));

__device__ __forceinline__ v2f vfma2(v2f a, v2f b, v2f c) {
#if __has_builtin(__builtin_elementwise_fma)
    return __builtin_elementwise_fma(a, b, c);
#else
    v2f r; r.x = fmaf(a.x, b.x, c.x); r.y = fmaf(a.y, b.y, c.y); return r;
#endif
}
__device__ __forceinline__ v2f splat2(float v) { v2f r; r.x = v; r.y = v; return r; }

#define CHI_F 0.15915494309189533577f
#define CLO_F ((float)(0.15915494309189533577 - (double)0.15915494309189533577f))
#define MAGIC_F 12582912.0f   // 1.5 * 2^23

// Packed radians -> revolutions; per-lane ops identical to scalar to_rev1.
__device__ __forceinline__ v2f to_rev2(v2f x) {
    v2f nb = vfma2(x, splat2(CHI_F), splat2(MAGIC_F));
    v2f n  = nb - splat2(MAGIC_F);
    v2f r  = vfma2(x, splat2(CHI_F), -n);
    return vfma2(x, splat2(CLO_F), r);
}

__device__ __forceinline__ float hw_sin_rev(float x) {
#if __has_builtin(__builtin_amdgcn_sinf)
    return __builtin_amdgcn_sinf(x);
#else
    return __sinf(x * 6.28318530717958647692f);
#endif
}
__device__ __forceinline__ float hw_cos_rev(float x) {
#if __has_builtin(__builtin_amdgcn_cosf)
    return __builtin_amdgcn_cosf(x);
#else
    return __cosf(x * 6.28318530717958647692f);
#endif
}

__global__ __launch_bounds__(256) void pend_kernel(
    const float* __restrict__ init,    // (B,2) theta, thdot
    const float* __restrict__ params,  // (B,4) omega, gamma, A, phi
    float* __restrict__ out,           // (B,1000)
    int B)
{
    int b = blockIdx.x * blockDim.x + threadIdx.x;
    if (b >= B) return;

    float th = init[2 * b + 0];
    float w  = init[2 * b + 1];
    const float omega = params[4 * b + 0];
    const float gamma = params[4 * b + 1];
    const float A     = params[4 * b + 2];
    const float phi   = params[4 * b + 3];

    const float dt  = 0.01f;
    const float hdt = 0.5f * dt;
    const float dt6 = dt / 6.0f;
    const float om2 = omega * omega;
    const float Fco = (A * omega) * omega;
    const float tp  = 6.28318530717958647692f * phi;

    v2f hd2; hd2.x = hdt; hd2.y = dt;      // (hdt, dt) for t2/t3 prep

    float4* out4 = (float4*)(out + (size_t)b * 1000);

    float fk = 0.0f;                    // tracks (float)k exactly (k < 2^24)

    auto step = [&]() -> float {
        // ---- forcing arguments (reference-exact radian values) ----
        float t  = fk * dt;             // == (float)k * dt bit-exact
        fk += 1.0f;
        v2f t23 = splat2(t) + hd2;      // (t+hdt, t+dt)   [pk_add]
        float y1 = tp * t;
        v2f y23 = splat2(tp) * t23;     // (y2, y3)        [pk_mul]

        // base reductions, packed: (th, y1) both ready at step top
        v2f base; base.x = th; base.y = y1;
        v2f rvB = to_rev2(base);        // (rvth, rvy1)
        float rvth = rvB.x;
        float rvy1 = rvB.y;

        // forcing deltas, packed
        v2f dy  = y23 - splat2(y1);                 // (y2-y1, y3-y1) [pk_add]
        v2f rvy = vfma2(dy, splat2(CHI_F), splat2(rvy1));  // [pk_fma]

        float c1 = hw_cos_rev(rvy1);
        float c2 = hw_cos_rev(rvy.x);   // shared by stages 2 and 3
        float c4 = hw_cos_rev(rvy.y);

        // ---- state chain (scalar; order identical to R9/R10) ----
        float sth  = hw_sin_rev(rvth);
        float th2  = fmaf(hdt, w, th);
        float s2   = hw_sin_rev(fmaf(th2 - th, CHI_F, rvth));

        float a1  = Fco * c1 - gamma * w   - om2 * sth;
        float w2_ = fmaf(hdt, a1, w);
        float a2  = Fco * c2 - gamma * w2_ - om2 * s2;
        float th3 = fmaf(hdt, w2_, th);
        float s3  = hw_sin_rev(fmaf(th3 - th, CHI_F, rvth));
        float w3_ = fmaf(hdt, a2, w);
        float a3  = Fco * c2 - gamma * w3_ - om2 * s3;
        float th4 = fmaf(dt, w3_, th);
        float s4  = hw_sin_rev(fmaf(th4 - th, CHI_F, rvth));
        float w4_ = fmaf(dt, a3, w);
        float a4  = Fco * c4 - gamma * w4_ - om2 * s4;

        // ---- combine: SCALAR (R9/R11 form) — no vector-gather movs ----
        float ks_th = w  + 2.0f * w2_ + 2.0f * w3_ + w4_;
        float ks_w  = a1 + 2.0f * a2  + 2.0f * a3  + a4;
        th = fmaf(dt6, ks_th, th);
        w  = fmaf(dt6, ks_w,  w);
        return th;
    };

    float4 ob;
    ob.x = th;
    ob.y = step();
    ob.z = step();
    ob.w = step();
    out4[0] = ob;

    for (int c = 1; c < 250; ++c) {
        ob.x = step();
        ob.y = step();
        ob.z = step();
        ob.w = step();
        out4[c] = ob;
    }
}

extern "C" void kernel_launch(void* const* d_in, const int* in_sizes, int n_in,
                              void* d_out, int out_size, void* d_ws, size_t ws_size,
                              hipStream_t stream) {
    const float* init   = (const float*)d_in[0];
    const float* params = (const float*)d_in[1];
    float* out = (float*)d_out;
    int B = in_sizes[0] / 2;

    int block = 256;
    int grid  = (B + block - 1) / block;
    hipLaunchKernelGGL(pend_kernel, dim3(grid), dim3(block), 0, stream,
                       init, params, out, B);
}

// Round 13
// 120.629 us; speedup vs baseline: 1.0297x; 1.0173x over previous
//
#include <hip/hip_runtime.h>

// PendulumSolver: B=65536 independent driven pendulums, RK4, 999 steps.
// Round 13: REVERT to round 10 verbatim — the best measured configuration
// (120.5 us). R12's scalar-combine hypothesis was wrong (122.7); R11's
// forcing-first grouping was wrong (124.2). Final structure:
//   - 1 thread = 1 pendulum, 256-thread blocks, 4-step unrolled body,
//     float4 output stores.
//   - All 7 trig per step via HW v_sin/v_cos (revolutions) at reference-exact
//     fp32 radian arguments; CW-split (Chi+Clo) radians->revolutions base
//     reduction, exact-delta sharing for secondary args.
//   - Packed fp32 (v_pk_*) for off-chain arithmetic: (t2,t3), (y2,y3),
//     base to_rev2(th,y1), (rvy2,rvy3), ks-combine, state update.
// Established by measurement: recons < direct HW trans (R5 vs R6); extra
// waves cannot add issue slots (R8); compiler scheduling is already optimal
// (R7, R11); absmax frozen at 0.0625 (1 bf16 ulp) across 12 implementations
// of the eval-error class; argument-class perturbations rejected (est. ~0.6
// amplified error vs 0.675 threshold).

typedef float v2f __attribute__((ext_vector_type(2)));

__device__ __forceinline__ v2f vfma2(v2f a, v2f b, v2f c) {
#if __has_builtin(__builtin_elementwise_fma)
    return __builtin_elementwise_fma(a, b, c);
#else
    v2f r; r.x = fmaf(a.x, b.x, c.x); r.y = fmaf(a.y, b.y, c.y); return r;
#endif
}
__device__ __forceinline__ v2f splat2(float v) { v2f r; r.x = v; r.y = v; return r; }

#define CHI_F 0.15915494309189533577f
#define CLO_F ((float)(0.15915494309189533577 - (double)0.15915494309189533577f))
#define MAGIC_F 12582912.0f   // 1.5 * 2^23

// Packed radians -> revolutions; per-lane ops identical to scalar to_rev1.
__device__ __forceinline__ v2f to_rev2(v2f x) {
    v2f nb = vfma2(x, splat2(CHI_F), splat2(MAGIC_F));
    v2f n  = nb - splat2(MAGIC_F);
    v2f r  = vfma2(x, splat2(CHI_F), -n);
    return vfma2(x, splat2(CLO_F), r);
}

__device__ __forceinline__ float hw_sin_rev(float x) {
#if __has_builtin(__builtin_amdgcn_sinf)
    return __builtin_amdgcn_sinf(x);
#else
    return __sinf(x * 6.28318530717958647692f);
#endif
}
__device__ __forceinline__ float hw_cos_rev(float x) {
#if __has_builtin(__builtin_amdgcn_cosf)
    return __builtin_amdgcn_cosf(x);
#else
    return __cosf(x * 6.28318530717958647692f);
#endif
}

__global__ __launch_bounds__(256) void pend_kernel(
    const float* __restrict__ init,    // (B,2) theta, thdot
    const float* __restrict__ params,  // (B,4) omega, gamma, A, phi
    float* __restrict__ out,           // (B,1000)
    int B)
{
    int b = blockIdx.x * blockDim.x + threadIdx.x;
    if (b >= B) return;

    float th = init[2 * b + 0];
    float w  = init[2 * b + 1];
    const float omega = params[4 * b + 0];
    const float gamma = params[4 * b + 1];
    const float A     = params[4 * b + 2];
    const float phi   = params[4 * b + 3];

    const float dt  = 0.01f;
    const float hdt = 0.5f * dt;
    const float dt6 = dt / 6.0f;
    const float om2 = omega * omega;
    const float Fco = (A * omega) * omega;
    const float tp  = 6.28318530717958647692f * phi;

    // packed constants
    v2f hd2; hd2.x = hdt; hd2.y = dt;      // (hdt, dt) for t2/t3 prep

    float4* out4 = (float4*)(out + (size_t)b * 1000);

    float fk = 0.0f;                    // tracks (float)k exactly (k < 2^24)

    auto step = [&]() -> float {
        // ---- forcing arguments (reference-exact radian values) ----
        float t  = fk * dt;             // == (float)k * dt bit-exact
        fk += 1.0f;
        v2f t23 = splat2(t) + hd2;      // (t+hdt, t+dt)   [pk_add]
        float y1 = tp * t;
        v2f y23 = splat2(tp) * t23;     // (y2, y3)        [pk_mul]

        // base reductions, packed: (th, y1) both ready at step top
        v2f base; base.x = th; base.y = y1;
        v2f rvB = to_rev2(base);        // (rvth, rvy1)
        float rvth = rvB.x;
        float rvy1 = rvB.y;

        // forcing deltas, packed
        v2f dy  = y23 - splat2(y1);                 // (y2-y1, y3-y1) [pk_add]
        v2f rvy = vfma2(dy, splat2(CHI_F), splat2(rvy1));  // [pk_fma]

        float c1 = hw_cos_rev(rvy1);
        float c2 = hw_cos_rev(rvy.x);   // shared by stages 2 and 3
        float c4 = hw_cos_rev(rvy.y);

        // ---- state chain (scalar; order identical to R9) ----
        float sth  = hw_sin_rev(rvth);
        float th2  = fmaf(hdt, w, th);
        float s2   = hw_sin_rev(fmaf(th2 - th, CHI_F, rvth));

        float a1  = Fco * c1 - gamma * w   - om2 * sth;
        float w2_ = fmaf(hdt, a1, w);
        float a2  = Fco * c2 - gamma * w2_ - om2 * s2;
        float th3 = fmaf(hdt, w2_, th);
        float s3  = hw_sin_rev(fmaf(th3 - th, CHI_F, rvth));
        float w3_ = fmaf(hdt, a2, w);
        float a3  = Fco * c2 - gamma * w3_ - om2 * s3;
        float th4 = fmaf(dt, w3_, th);
        float s4  = hw_sin_rev(fmaf(th4 - th, CHI_F, rvth));
        float w4_ = fmaf(dt, a3, w);
        float a4  = Fco * c4 - gamma * w4_ - om2 * s4;

        // ---- combine, packed: lane ops match R9's scalar eval order ----
        v2f U1; U1.x = w;   U1.y = a1;
        v2f U2; U2.x = w2_; U2.y = a2;
        v2f U3; U3.x = w3_; U3.y = a3;
        v2f U4; U4.x = w4_; U4.y = a4;
        v2f ks = vfma2(splat2(2.0f), U2, U1);   // w + 2*w2_        [pk_fma]
        ks = vfma2(splat2(2.0f), U3, ks);       // .. + 2*w3_       [pk_fma]
        ks = ks + U4;                           // .. + w4_         [pk_add]
        v2f Y; Y.x = th; Y.y = w;
        Y = vfma2(splat2(dt6), ks, Y);          // state update     [pk_fma]
        th = Y.x;
        w  = Y.y;
        return th;
    };

    float4 ob;
    ob.x = th;
    ob.y = step();
    ob.z = step();
    ob.w = step();
    out4[0] = ob;

    for (int c = 1; c < 250; ++c) {
        ob.x = step();
        ob.y = step();
        ob.z = step();
        ob.w = step();
        out4[c] = ob;
    }
}

extern "C" void kernel_launch(void* const* d_in, const int* in_sizes, int n_in,
                              void* d_out, int out_size, void* d_ws, size_t ws_size,
                              hipStream_t stream) {
    const float* init   = (const float*)d_in[0];
    const float* params = (const float*)d_in[1];
    float* out = (float*)d_out;
    int B = in_sizes[0] / 2;

    int block = 256;
    int grid  = (B + block - 1) / block;
    hipLaunchKernelGGL(pend_kernel, dim3(grid), dim3(block), 0, stream,
                       init, params, out, B);
}